// Round 14
// baseline (144.035 us; speedup 1.0000x reference)
//
#include <hip/hip_runtime.h>
#include <hip/hip_bf16.h>
#include <stdint.h>
#include <stddef.h>

#define T_S 4096
#define D_M 1024
#define NH_ 16
#define EPSF 1.1920929e-07f
// 0.125 (1/sqrt(64)) * log2(e): folded into q so attn uses exp2 with no mul/max
#define QSCALE 0.1803368801111204f

typedef float f32x4 __attribute__((ext_vector_type(4)));
typedef __bf16 bf16x8 __attribute__((ext_vector_type(8)));
typedef short short8 __attribute__((ext_vector_type(8)));
typedef unsigned short ushort4v __attribute__((ext_vector_type(4)));

static __device__ __forceinline__ unsigned short f2bf(float f) {
  return __builtin_bit_cast(unsigned short, (__bf16)f);  // native RNE cvt
}

#define GLDS16(gp, lp) __builtin_amdgcn_global_load_lds( \
    (__attribute__((address_space(1))) void*)(gp),       \
    (__attribute__((address_space(3))) void*)(lp), 16, 0, 0)

static __device__ __forceinline__ f32x4 mfma16(bf16x8 a, bf16x8 b, f32x4 c) {
  return __builtin_amdgcn_mfma_f32_16x16x32_bf16(a, b, c, 0, 0, 0);
}

// ---------------- RoPE cos/sin table: [T][32] ----------------
__global__ __launch_bounds__(256) void k_rope_tab(float* __restrict__ cosT,
                                                  float* __restrict__ sinT) {
  int i = blockIdx.x * 256 + threadIdx.x;  // t*32 + f
  int t = i >> 5, f = i & 31;
  float fr = (f < 16) ? powf(1e-4f, (float)f * (1.0f / 15.0f)) : 0.0f;
  float th = (float)t * fr;
  cosT[i] = cosf(th);
  sinT[i] = sinf(th);
}

// ---------------- f32 -> bf16, both weights in one launch ----------------
__global__ __launch_bounds__(256) void k_cast_weights(const float* __restrict__ qkvw,
                                                      unsigned short* __restrict__ qkvwb,
                                                      const float* __restrict__ ow,
                                                      unsigned short* __restrict__ owb) {
  int i = blockIdx.x * 256 + threadIdx.x;
  const float* src;
  unsigned short* dst;
  int idx;
  if (i < 786432) {
    src = qkvw; dst = qkvwb; idx = i;
  } else {
    src = ow; dst = owb; idx = i - 786432;
  }
  float4 v = ((const float4*)src)[idx];
  ushort4v o;
  o.x = f2bf(v.x); o.y = f2bf(v.y); o.z = f2bf(v.z); o.w = f2bf(v.w);
  ((ushort4v*)dst)[idx] = o;
}

// ---------------- RMSNorm over D=1024 + cast ----------------
__global__ __launch_bounds__(256) void k_rmsnorm_cast(const float* __restrict__ x,
                                                      unsigned short* __restrict__ xn) {
  const int row = blockIdx.x;
  const int tid = threadIdx.x;
  float4 v = ((const float4*)(x + (size_t)row * D_M))[tid];
  float ss = v.x * v.x + v.y * v.y + v.z * v.z + v.w * v.w;
#pragma unroll
  for (int d = 1; d < 64; d <<= 1) ss += __shfl_xor(ss, d, 64);
  __shared__ float red[4];
  if ((tid & 63) == 0) red[tid >> 6] = ss;
  __syncthreads();
  float sc = rsqrtf((red[0] + red[1] + red[2] + red[3]) * (1.0f / D_M) + EPSF);
  ushort4v o;
  o.x = f2bf(v.x * sc); o.y = f2bf(v.y * sc); o.z = f2bf(v.z * sc); o.w = f2bf(v.w * sc);
  ((ushort4v*)(xn + (size_t)row * D_M))[tid] = o;
}

// ---------------- bf16 GEMM, C = A @ B^T, 3-stage pipeline (R8 champion) ----------------
// BM=256, BN=128, BK=32; 8 waves (4M x 2N), wave tile 64x64; 3 LDS buffers x 24KB.
// EPI 0: fused per-head RMSNorm+RoPE scatter -> q/k/v head-major bf16 [n,h,t,d].
//        q additionally scaled by QSCALE (softmax scale * log2e) so attn uses raw exp2.
// EPI 1: Cf = resid + scale[col]*acc (f32)
template <int EPI>
__global__ __launch_bounds__(512) void k_gemm256(
    const unsigned short* __restrict__ A, const unsigned short* __restrict__ B,
    unsigned short* __restrict__ q_out, unsigned short* __restrict__ k_out,
    unsigned short* __restrict__ v_out, float* __restrict__ Cf,
    const float* __restrict__ resid, const float* __restrict__ scale,
    const float* __restrict__ cosT, const float* __restrict__ sinT,
    int M, int Ncols, int K) {
  extern __shared__ __align__(16) char lds[];  // 3 x (16384 A + 8192 B) = 73728 B
  const int tid = threadIdx.x;
  const int lane = tid & 63, w = tid >> 6;
  const int lrow = lane & 15, g = lane >> 4;
  const int wm = w >> 1, wn = w & 1;
  const int m0 = blockIdx.y * 256, n0 = blockIdx.x * 128;
  const int NT = K >> 5;

  const int srcgrp = (((tid & 3) ^ ((tid >> 3) & 3)) << 3);
  const size_t aoff0 = (size_t)(m0 + (tid >> 2)) * K + srcgrp;
  const size_t aoff1 = aoff0 + (size_t)128 * K;
  const size_t boff = (size_t)(n0 + (tid >> 2)) * K + srcgrp;
  const int wbase = w * 1024;

  int abyte[4], bbyte[4];
#pragma unroll
  for (int i = 0; i < 4; ++i) {
    int ar = wm * 64 + i * 16 + lrow;
    abyte[i] = ar * 64 + ((g ^ ((ar >> 1) & 3)) << 4);
    int br = wn * 64 + i * 16 + lrow;
    bbyte[i] = 16384 + br * 64 + ((g ^ ((br >> 1) & 3)) << 4);
  }

  f32x4 acc[4][4] = {};

#pragma unroll
  for (int t = 0; t < 2; ++t) {
    char* sp = lds + t * 24576;
    GLDS16(A + aoff0 + t * 32, sp + wbase);
    GLDS16(A + aoff1 + t * 32, sp + 8192 + wbase);
    GLDS16(B + boff + t * 32, sp + 16384 + wbase);
  }
  asm volatile("s_waitcnt vmcnt(3)" ::: "memory");
  __builtin_amdgcn_s_barrier();
  asm volatile("" ::: "memory");

  int cb = 0, sb = 49152;
  for (int t = 0; t < NT; ++t) {
    if (t + 2 < NT) {
      const int kt2 = (t + 2) << 5;
      char* sp = lds + sb;
      GLDS16(A + aoff0 + kt2, sp + wbase);
      GLDS16(A + aoff1 + kt2, sp + 8192 + wbase);
      GLDS16(B + boff + kt2, sp + 16384 + wbase);
    }
    const char* cp = lds + cb;
    bf16x8 aF[4], bF[4];
#pragma unroll
    for (int i = 0; i < 4; ++i) aF[i] = *(const bf16x8*)(cp + abyte[i]);
#pragma unroll
    for (int i = 0; i < 4; ++i) bF[i] = *(const bf16x8*)(cp + bbyte[i]);
    __builtin_amdgcn_s_setprio(1);
#pragma unroll
    for (int mi = 0; mi < 4; ++mi)
#pragma unroll
      for (int ni = 0; ni < 4; ++ni)
        acc[mi][ni] = mfma16(aF[mi], bF[ni], acc[mi][ni]);
    __builtin_amdgcn_s_setprio(0);
    if (t + 2 < NT)
      asm volatile("s_waitcnt vmcnt(3)" ::: "memory");
    else
      asm volatile("s_waitcnt vmcnt(0)" ::: "memory");
    __builtin_amdgcn_s_barrier();
    asm volatile("" ::: "memory");
    cb += 24576; if (cb == 73728) cb = 0;
    sb += 24576; if (sb == 73728) sb = 0;
  }

  const int rbase = m0 + wm * 64 + g * 4;  // + mi*16 + j
  const int colbase = n0 + wn * 64;        // wave covers exactly one head

  if (EPI == 1) {
#pragma unroll
    for (int mi = 0; mi < 4; ++mi)
#pragma unroll
      for (int nf = 0; nf < 4; ++nf) {
        int col = colbase + nf * 16 + lrow;
        float sc = scale[col];
#pragma unroll
        for (int j = 0; j < 4; ++j) {
          int row = rbase + mi * 16 + j;
          size_t idx = (size_t)row * Ncols + col;
          Cf[idx] = resid[idx] + sc * acc[mi][nf][j];
        }
      }
  } else {
    const int which = colbase >> 10;
    const int hh = (colbase >> 6) & 15;
    if (which == 2) {
#pragma unroll
      for (int mi = 0; mi < 4; ++mi)
#pragma unroll
        for (int j = 0; j < 4; ++j) {
          int row = rbase + mi * 16 + j;
          int t = row & (T_S - 1), nn = row >> 12;
          size_t ob = ((size_t)(nn * NH_ + hh) * T_S + t) * 64;
#pragma unroll
          for (int nf = 0; nf < 4; ++nf)
            v_out[ob + nf * 16 + lrow] = f2bf(acc[mi][nf][j]);
        }
    } else {
      unsigned short* dst = which ? k_out : q_out;
      const float post = which ? 1.0f : QSCALE;  // fold softmax scale*log2e into q
#pragma unroll
      for (int mi = 0; mi < 4; ++mi)
#pragma unroll
        for (int j = 0; j < 4; ++j) {
          int row = rbase + mi * 16 + j;
          int t = row & (T_S - 1), nn = row >> 12;
          float ss = 0.0f;
#pragma unroll
          for (int nf = 0; nf < 4; ++nf) ss += acc[mi][nf][j] * acc[mi][nf][j];
          ss += __shfl_xor(ss, 1, 64);
          ss += __shfl_xor(ss, 2, 64);
          ss += __shfl_xor(ss, 4, 64);
          ss += __shfl_xor(ss, 8, 64);
          float sc = rsqrtf(ss * (1.0f / 64.0f) + EPSF) * post;
          size_t ob = ((size_t)(nn * NH_ + hh) * T_S + t) * 64;
#pragma unroll
          for (int nf = 0; nf < 2; ++nf) {
            int dd = nf * 16 + lrow;
            float cs = cosT[t * 32 + dd], sn = sinT[t * 32 + dd];
            float z1 = acc[mi][nf][j] * sc, z2 = acc[mi][nf + 2][j] * sc;
            dst[ob + dd] = f2bf(z1 * cs + z2 * sn);
            dst[ob + dd + 32] = f2bf(z2 * cs - z1 * sn);
          }
        }
    }
  }
}

// ---------------- chunked sliding-window attention (windowed, T14 async-V) ----------------
// Softmax without max-pass: |q|,|k| <= 8 after RMS (RoPE preserves norm) =>
// score*log2e <= 11.6, exp2 never overflows; masked -> exp2(-1e30) = 0.
__global__ __launch_bounds__(256, 2) void k_attn(const unsigned short* __restrict__ qh,
                                                 const unsigned short* __restrict__ kh,
                                                 const unsigned short* __restrict__ vh,
                                                 unsigned short* __restrict__ ao) {
  extern __shared__ __align__(16) char lds[];
  unsigned short* Vt = (unsigned short*)lds;                    // [64][264]
  unsigned short* Pb = (unsigned short*)(lds + 64 * 264 * 2);   // 4 x [32][72]
  const int b = blockIdx.x;
  const int c = b & 31, nh = b >> 5;
  const int tid = threadIdx.x, lane = tid & 63, w = tid >> 6;
  const int lrow = lane & 15, g = lane >> 4, lk8 = g * 8;
  const size_t hb = (size_t)nh * T_S * 64;
  const unsigned short* qg = qh + hb + (size_t)c * 128 * 64;
  const unsigned short* kg = kh + hb + ((ptrdiff_t)c * 128 - 128) * 64;
  const unsigned short* vg = vh + hb + ((ptrdiff_t)c * 128 - 128) * 64;

  // ---- issue V loads early (consumed after softmax) ----
  const int m_idx = (tid & 7) | ((tid >> 6) << 3);
  const int m0v = m_idx * 8;
  const int d0 = ((tid >> 3) & 7) * 8;
  short8 vv[8];
#pragma unroll
  for (int i = 0; i < 8; ++i) {
    short8 z = {0, 0, 0, 0, 0, 0, 0, 0};
    if (!(c == 0 && m0v < 128)) z = *(const short8*)(vg + (size_t)(m0v + i) * 64 + d0);
    vv[i] = z;
  }

  // Q fragments
  bf16x8 qf[2][2];
#pragma unroll
  for (int mi = 0; mi < 2; ++mi)
#pragma unroll
    for (int ks = 0; ks < 2; ++ks)
      qf[mi][ks] =
          *(const bf16x8*)(qg + (size_t)(w * 32 + mi * 16 + lrow) * 64 + ks * 32 + lk8);

  // S = Q K^T over the wave's 10-tile window (scores pre-scaled by 0.125*log2e via q)
  const int nlo = 2 * w;
  f32x4 s[2][10] = {};
#pragma unroll
  for (int u = 0; u < 10; ++u) {
    const int ni = nlo + u;
    if (c == 0 && ni < 8) continue;
    bf16x8 kf0 = *(const bf16x8*)(kg + (size_t)(ni * 16 + lrow) * 64 + lk8);
    bf16x8 kf1 = *(const bf16x8*)(kg + (size_t)(ni * 16 + lrow) * 64 + 32 + lk8);
#pragma unroll
    for (int mi = 0; mi < 2; ++mi) {
      s[mi][u] = mfma16(qf[mi][0], kf0, s[mi][u]);
      s[mi][u] = mfma16(qf[mi][1], kf1, s[mi][u]);
    }
  }

  // mask + exp2 + row-sum (no max pass; deferred normalization)
  float invs[2][4];
#pragma unroll
  for (int mi = 0; mi < 2; ++mi) {
#pragma unroll
    for (int j = 0; j < 4; ++j) {
      int jq = w * 32 + mi * 16 + g * 4 + j;
      float sum = 0.0f;
#pragma unroll
      for (int u = 0; u < 10; ++u) {
        int m = (nlo + u) * 16 + lrow;
        bool ok = (m > jq) && (m <= 128 + jq) && (c > 0 || m >= 128);
        float p = ok ? exp2f(s[mi][u][j]) : 0.0f;
        s[mi][u][j] = p;
        sum += p;
      }
#pragma unroll
      for (int d2 = 1; d2 < 16; d2 <<= 1) sum += __shfl_xor(sum, d2, 64);
      invs[mi][j] = 1.0f / sum;
    }
  }

  // ---- now commit V to LDS (transposed), then sync ----
#pragma unroll
  for (int jj = 0; jj < 8; ++jj) {
    short8 wv;
#pragma unroll
    for (int i = 0; i < 8; ++i) wv[i] = vv[i][jj];
    *(short8*)(Vt + (size_t)(d0 + jj) * 264 + m0v) = wv;
  }
  __syncthreads();  // Vt staged before PV reads

  // PV over 3 quarters; P staged per-wave in LDS (stride 72), unnormalized
  f32x4 oacc[2][4] = {};
  unsigned short* Pw = Pb + w * (32 * 72);
  const int qlo = w >> 1;
#pragma unroll
  for (int qq = 0; qq < 3; ++qq) {
#pragma unroll
    for (int mi = 0; mi < 2; ++mi)
#pragma unroll
      for (int ni4 = 0; ni4 < 4; ++ni4)
#pragma unroll
        for (int j = 0; j < 4; ++j) {
          int r = mi * 16 + g * 4 + j;
          float val;
          if ((w & 1) == 0) {
            int u = qq * 4 + ni4;
            val = (u < 10) ? s[mi][u < 10 ? u : 0][j] : 0.0f;
          } else {
            int u = qq * 4 + ni4 - 2;
            val = (u >= 0 && u < 10) ? s[mi][(u >= 0 && u < 10) ? u : 0][j] : 0.0f;
          }
          Pw[r * 72 + ni4 * 16 + lrow] = f2bf(val);
        }
    const int qi = qlo + qq;
#pragma unroll
    for (int ks = 0; ks < 2; ++ks) {
      bf16x8 pf[2], vf[4];
#pragma unroll
      for (int mi = 0; mi < 2; ++mi)
        pf[mi] = *(const bf16x8*)&Pw[(mi * 16 + lrow) * 72 + ks * 32 + lk8];
#pragma unroll
      for (int nj = 0; nj < 4; ++nj)
        vf[nj] = *(const bf16x8*)&Vt[(nj * 16 + lrow) * 264 + qi * 64 + ks * 32 + lk8];
#pragma unroll
      for (int mi = 0; mi < 2; ++mi)
#pragma unroll
        for (int nj = 0; nj < 4; ++nj)
          oacc[mi][nj] = mfma16(pf[mi], vf[nj], oacc[mi][nj]);
    }
  }

  const int t0 = c * 128 + w * 32;
  const int n_ = nh >> 4, h_ = nh & 15;
#pragma unroll
  for (int mi = 0; mi < 2; ++mi)
#pragma unroll
    for (int nj = 0; nj < 4; ++nj)
#pragma unroll
      for (int j = 0; j < 4; ++j) {
        int t = t0 + mi * 16 + g * 4 + j;
        int dcol = nj * 16 + lrow;
        ao[((size_t)n_ * T_S + t) * D_M + h_ * 64 + dcol] =
            f2bf(oacc[mi][nj][j] * invs[mi][j]);
      }
}

extern "C" void kernel_launch(void* const* d_in, const int* in_sizes, int n_in,
                              void* d_out, int out_size, void* d_ws, size_t ws_size,
                              hipStream_t stream) {
  const float* x = (const float*)d_in[0];      // [2,4096,1024]
  const float* qkvw = (const float*)d_in[1];   // [3,1024,1024]
  const float* ow = (const float*)d_in[2];     // [1024,1024]
  const float* osc = (const float*)d_in[3];    // [1024]
  float* out = (float*)d_out;

  char* ws = (char*)d_ws;
  unsigned short* xn = (unsigned short*)(ws + 0);
  unsigned short* qkvwb = (unsigned short*)(ws + 16777216);
  unsigned short* owb = (unsigned short*)(ws + 23068672);
  unsigned short* qhb = (unsigned short*)(ws + 25165824);
  unsigned short* khb = (unsigned short*)(ws + 41943040);
  unsigned short* vhb = (unsigned short*)(ws + 58720256);
  unsigned short* aob = (unsigned short*)(ws + 75497472);
  float* cosT = (float*)(ws + 92274688);
  float* sinT = (float*)(ws + 92798976);

  k_rope_tab<<<512, 256, 0, stream>>>(cosT, sinT);
  k_cast_weights<<<4096, 256, 0, stream>>>(qkvw, qkvwb, ow, owb);
  k_rmsnorm_cast<<<8192, 256, 0, stream>>>(x, xn);
  k_gemm256<0><<<dim3(24, 32), 512, 73728, stream>>>(xn, qkvwb, qhb, khb, vhb, nullptr,
                                                     nullptr, nullptr, cosT, sinT,
                                                     8192, 3072, 1024);
  k_attn<<<1024, 256, 52224, stream>>>(qhb, khb, vhb, aob);
  k_gemm256<1><<<dim3(8, 32), 512, 73728, stream>>>(aob, owb, nullptr, nullptr, nullptr,
                                                    out, x, osc, nullptr, nullptr,
                                                    8192, 1024, 1024);
}

// Round 16
// 138.486 us; speedup vs baseline: 1.0401x; 1.0401x over previous
//
#include <hip/hip_runtime.h>
#include <hip/hip_bf16.h>
#include <stdint.h>
#include <stddef.h>

#define T_S 4096
#define D_M 1024
#define NH_ 16
#define EPSF 1.1920929e-07f

typedef float f32x4 __attribute__((ext_vector_type(4)));
typedef __bf16 bf16x8 __attribute__((ext_vector_type(8)));
typedef short short8 __attribute__((ext_vector_type(8)));
typedef unsigned short ushort4v __attribute__((ext_vector_type(4)));

static __device__ __forceinline__ unsigned short f2bf(float f) {
  return __builtin_bit_cast(unsigned short, (__bf16)f);  // native RNE cvt
}

#define GLDS16(gp, lp) __builtin_amdgcn_global_load_lds( \
    (__attribute__((address_space(1))) void*)(gp),       \
    (__attribute__((address_space(3))) void*)(lp), 16, 0, 0)

static __device__ __forceinline__ f32x4 mfma16(bf16x8 a, bf16x8 b, f32x4 c) {
  return __builtin_amdgcn_mfma_f32_16x16x32_bf16(a, b, c, 0, 0, 0);
}

// ---------------- fused prologue: rmsnorm+cast | weight casts | rope table ----------------
// Block partition (cumulative, grid = 12800):
//   [0, 8192)      RMSNorm rows (8192)
//   [8192, 11264)  qkvw cast (3072 blocks x 256 thr x float4 = 786432 groups)
//   [11264, 12288) ow cast (1024 blocks = 262144 groups)
//   [12288, 12800) rope table (512 blocks = 131072 entries)
__global__ __launch_bounds__(256) void k_prologue(
    const float* __restrict__ x, unsigned short* __restrict__ xn,
    const float* __restrict__ qkvw, unsigned short* __restrict__ qkvwb,
    const float* __restrict__ ow, unsigned short* __restrict__ owb,
    float* __restrict__ cosT, float* __restrict__ sinT) {
  const int bid = blockIdx.x;
  const int tid = threadIdx.x;
  if (bid < 8192) {
    // RMSNorm over D=1024 + cast, one block per token
    const int row = bid;
    float4 v = ((const float4*)(x + (size_t)row * D_M))[tid];
    float ss = v.x * v.x + v.y * v.y + v.z * v.z + v.w * v.w;
#pragma unroll
    for (int d = 1; d < 64; d <<= 1) ss += __shfl_xor(ss, d, 64);
    __shared__ float red[4];
    if ((tid & 63) == 0) red[tid >> 6] = ss;
    __syncthreads();
    float sc = rsqrtf((red[0] + red[1] + red[2] + red[3]) * (1.0f / D_M) + EPSF);
    ushort4v o;
    o.x = f2bf(v.x * sc); o.y = f2bf(v.y * sc);
    o.z = f2bf(v.z * sc); o.w = f2bf(v.w * sc);
    ((ushort4v*)(xn + (size_t)row * D_M))[tid] = o;
  } else if (bid < 11264) {
    // qkvw f32 -> bf16
    int i = (bid - 8192) * 256 + tid;
    float4 v = ((const float4*)qkvw)[i];
    ushort4v o;
    o.x = f2bf(v.x); o.y = f2bf(v.y); o.z = f2bf(v.z); o.w = f2bf(v.w);
    ((ushort4v*)qkvwb)[i] = o;
  } else if (bid < 12288) {
    // ow f32 -> bf16
    int i = (bid - 11264) * 256 + tid;
    float4 v = ((const float4*)ow)[i];
    ushort4v o;
    o.x = f2bf(v.x); o.y = f2bf(v.y); o.z = f2bf(v.z); o.w = f2bf(v.w);
    ((ushort4v*)owb)[i] = o;
  } else {
    // RoPE cos/sin table [T][32]
    int i = (bid - 12288) * 256 + tid;  // t*32 + f
    int t = i >> 5, f = i & 31;
    float fr = (f < 16) ? powf(1e-4f, (float)f * (1.0f / 15.0f)) : 0.0f;
    float th = (float)t * fr;
    cosT[i] = cosf(th);
    sinT[i] = sinf(th);
  }
}

// ---------------- bf16 GEMM, C = A @ B^T, 3-stage pipeline (R8/R13 champion) ----------------
// BM=256, BN=128, BK=32; 8 waves (4M x 2N), wave tile 64x64; 3 LDS buffers x 24KB.
// Session-closed GEMM search: schedule depth (R5-R7), occupancy coercion (R9-R10),
// wave-tile intensity (R12) all lose to this config. VGPR 56, 2 blocks/CU, vmcnt(3).
// EPI 0: fused per-head RMSNorm+RoPE scatter -> q/k/v head-major bf16 [n,h,t,d]
// EPI 1: Cf = resid + scale[col]*acc (f32)
template <int EPI>
__global__ __launch_bounds__(512) void k_gemm256(
    const unsigned short* __restrict__ A, const unsigned short* __restrict__ B,
    unsigned short* __restrict__ q_out, unsigned short* __restrict__ k_out,
    unsigned short* __restrict__ v_out, float* __restrict__ Cf,
    const float* __restrict__ resid, const float* __restrict__ scale,
    const float* __restrict__ cosT, const float* __restrict__ sinT,
    int M, int Ncols, int K) {
  extern __shared__ __align__(16) char lds[];  // 3 x (16384 A + 8192 B) = 73728 B
  const int tid = threadIdx.x;
  const int lane = tid & 63, w = tid >> 6;
  const int lrow = lane & 15, g = lane >> 4;
  const int wm = w >> 1, wn = w & 1;
  const int m0 = blockIdx.y * 256, n0 = blockIdx.x * 128;
  const int NT = K >> 5;

  const int srcgrp = (((tid & 3) ^ ((tid >> 3) & 3)) << 3);
  const size_t aoff0 = (size_t)(m0 + (tid >> 2)) * K + srcgrp;
  const size_t aoff1 = aoff0 + (size_t)128 * K;
  const size_t boff = (size_t)(n0 + (tid >> 2)) * K + srcgrp;
  const int wbase = w * 1024;

  int abyte[4], bbyte[4];
#pragma unroll
  for (int i = 0; i < 4; ++i) {
    int ar = wm * 64 + i * 16 + lrow;
    abyte[i] = ar * 64 + ((g ^ ((ar >> 1) & 3)) << 4);
    int br = wn * 64 + i * 16 + lrow;
    bbyte[i] = 16384 + br * 64 + ((g ^ ((br >> 1) & 3)) << 4);
  }

  f32x4 acc[4][4] = {};

#pragma unroll
  for (int t = 0; t < 2; ++t) {
    char* sp = lds + t * 24576;
    GLDS16(A + aoff0 + t * 32, sp + wbase);
    GLDS16(A + aoff1 + t * 32, sp + 8192 + wbase);
    GLDS16(B + boff + t * 32, sp + 16384 + wbase);
  }
  asm volatile("s_waitcnt vmcnt(3)" ::: "memory");
  __builtin_amdgcn_s_barrier();
  asm volatile("" ::: "memory");

  int cb = 0, sb = 49152;
  for (int t = 0; t < NT; ++t) {
    if (t + 2 < NT) {
      const int kt2 = (t + 2) << 5;
      char* sp = lds + sb;
      GLDS16(A + aoff0 + kt2, sp + wbase);
      GLDS16(A + aoff1 + kt2, sp + 8192 + wbase);
      GLDS16(B + boff + kt2, sp + 16384 + wbase);
    }
    const char* cp = lds + cb;
    bf16x8 aF[4], bF[4];
#pragma unroll
    for (int i = 0; i < 4; ++i) aF[i] = *(const bf16x8*)(cp + abyte[i]);
#pragma unroll
    for (int i = 0; i < 4; ++i) bF[i] = *(const bf16x8*)(cp + bbyte[i]);
    __builtin_amdgcn_s_setprio(1);
#pragma unroll
    for (int mi = 0; mi < 4; ++mi)
#pragma unroll
      for (int ni = 0; ni < 4; ++ni)
        acc[mi][ni] = mfma16(aF[mi], bF[ni], acc[mi][ni]);
    __builtin_amdgcn_s_setprio(0);
    if (t + 2 < NT)
      asm volatile("s_waitcnt vmcnt(3)" ::: "memory");
    else
      asm volatile("s_waitcnt vmcnt(0)" ::: "memory");
    __builtin_amdgcn_s_barrier();
    asm volatile("" ::: "memory");
    cb += 24576; if (cb == 73728) cb = 0;
    sb += 24576; if (sb == 73728) sb = 0;
  }

  const int rbase = m0 + wm * 64 + g * 4;  // + mi*16 + j
  const int colbase = n0 + wn * 64;        // wave covers exactly one head

  if (EPI == 1) {
#pragma unroll
    for (int mi = 0; mi < 4; ++mi)
#pragma unroll
      for (int nf = 0; nf < 4; ++nf) {
        int col = colbase + nf * 16 + lrow;
        float sc = scale[col];
#pragma unroll
        for (int j = 0; j < 4; ++j) {
          int row = rbase + mi * 16 + j;
          size_t idx = (size_t)row * Ncols + col;
          Cf[idx] = resid[idx] + sc * acc[mi][nf][j];
        }
      }
  } else {
    const int which = colbase >> 10;
    const int hh = (colbase >> 6) & 15;
    if (which == 2) {
#pragma unroll
      for (int mi = 0; mi < 4; ++mi)
#pragma unroll
        for (int j = 0; j < 4; ++j) {
          int row = rbase + mi * 16 + j;
          int t = row & (T_S - 1), nn = row >> 12;
          size_t ob = ((size_t)(nn * NH_ + hh) * T_S + t) * 64;
#pragma unroll
          for (int nf = 0; nf < 4; ++nf)
            v_out[ob + nf * 16 + lrow] = f2bf(acc[mi][nf][j]);
        }
    } else {
      unsigned short* dst = which ? k_out : q_out;
#pragma unroll
      for (int mi = 0; mi < 4; ++mi)
#pragma unroll
        for (int j = 0; j < 4; ++j) {
          int row = rbase + mi * 16 + j;
          int t = row & (T_S - 1), nn = row >> 12;
          float ss = 0.0f;
#pragma unroll
          for (int nf = 0; nf < 4; ++nf) ss += acc[mi][nf][j] * acc[mi][nf][j];
          ss += __shfl_xor(ss, 1, 64);
          ss += __shfl_xor(ss, 2, 64);
          ss += __shfl_xor(ss, 4, 64);
          ss += __shfl_xor(ss, 8, 64);
          float sc = rsqrtf(ss * (1.0f / 64.0f) + EPSF);
          size_t ob = ((size_t)(nn * NH_ + hh) * T_S + t) * 64;
#pragma unroll
          for (int nf = 0; nf < 2; ++nf) {
            int dd = nf * 16 + lrow;
            float cs = cosT[t * 32 + dd], sn = sinT[t * 32 + dd];
            float z1 = acc[mi][nf][j] * sc, z2 = acc[mi][nf + 2][j] * sc;
            dst[ob + dd] = f2bf(z1 * cs + z2 * sn);
            dst[ob + dd + 32] = f2bf(z2 * cs - z1 * sn);
          }
        }
    }
  }
}

// ---------------- chunked sliding-window attention (windowed, T14 async-V) ----------------
__global__ __launch_bounds__(256, 2) void k_attn(const unsigned short* __restrict__ qh,
                                                 const unsigned short* __restrict__ kh,
                                                 const unsigned short* __restrict__ vh,
                                                 unsigned short* __restrict__ ao) {
  extern __shared__ __align__(16) char lds[];
  unsigned short* Vt = (unsigned short*)lds;                    // [64][264]
  unsigned short* Pb = (unsigned short*)(lds + 64 * 264 * 2);   // 4 x [32][72]
  const int b = blockIdx.x;
  const int c = b & 31, nh = b >> 5;
  const int tid = threadIdx.x, lane = tid & 63, w = tid >> 6;
  const int lrow = lane & 15, g = lane >> 4, lk8 = g * 8;
  const size_t hb = (size_t)nh * T_S * 64;
  const unsigned short* qg = qh + hb + (size_t)c * 128 * 64;
  const unsigned short* kg = kh + hb + ((ptrdiff_t)c * 128 - 128) * 64;
  const unsigned short* vg = vh + hb + ((ptrdiff_t)c * 128 - 128) * 64;

  // ---- issue V loads early (consumed after softmax) ----
  const int m_idx = (tid & 7) | ((tid >> 6) << 3);
  const int m0v = m_idx * 8;
  const int d0 = ((tid >> 3) & 7) * 8;
  short8 vv[8];
#pragma unroll
  for (int i = 0; i < 8; ++i) {
    short8 z = {0, 0, 0, 0, 0, 0, 0, 0};
    if (!(c == 0 && m0v < 128)) z = *(const short8*)(vg + (size_t)(m0v + i) * 64 + d0);
    vv[i] = z;
  }

  // Q fragments
  bf16x8 qf[2][2];
#pragma unroll
  for (int mi = 0; mi < 2; ++mi)
#pragma unroll
    for (int ks = 0; ks < 2; ++ks)
      qf[mi][ks] =
          *(const bf16x8*)(qg + (size_t)(w * 32 + mi * 16 + lrow) * 64 + ks * 32 + lk8);

  // S = Q K^T over the wave's 10-tile window
  const int nlo = 2 * w;
  f32x4 s[2][10] = {};
#pragma unroll
  for (int u = 0; u < 10; ++u) {
    const int ni = nlo + u;
    if (c == 0 && ni < 8) continue;
    bf16x8 kf0 = *(const bf16x8*)(kg + (size_t)(ni * 16 + lrow) * 64 + lk8);
    bf16x8 kf1 = *(const bf16x8*)(kg + (size_t)(ni * 16 + lrow) * 64 + 32 + lk8);
#pragma unroll
    for (int mi = 0; mi < 2; ++mi) {
      s[mi][u] = mfma16(qf[mi][0], kf0, s[mi][u]);
      s[mi][u] = mfma16(qf[mi][1], kf1, s[mi][u]);
    }
  }

  // mask + scale + row softmax (deferred normalization)
  float invs[2][4];
#pragma unroll
  for (int mi = 0; mi < 2; ++mi) {
#pragma unroll
    for (int j = 0; j < 4; ++j) {
      int jq = w * 32 + mi * 16 + g * 4 + j;
      float mx = -1e30f;
#pragma unroll
      for (int u = 0; u < 10; ++u) {
        int m = (nlo + u) * 16 + lrow;
        bool ok = (m > jq) && (m <= 128 + jq) && (c > 0 || m >= 128);
        float val = ok ? s[mi][u][j] * 0.125f : -1e30f;
        s[mi][u][j] = val;
        mx = fmaxf(mx, val);
      }
#pragma unroll
      for (int d2 = 1; d2 < 16; d2 <<= 1) mx = fmaxf(mx, __shfl_xor(mx, d2, 64));
      float sum = 0.0f;
#pragma unroll
      for (int u = 0; u < 10; ++u) {
        float p = __expf(s[mi][u][j] - mx);
        s[mi][u][j] = p;
        sum += p;
      }
#pragma unroll
      for (int d2 = 1; d2 < 16; d2 <<= 1) sum += __shfl_xor(sum, d2, 64);
      invs[mi][j] = 1.0f / sum;
    }
  }

  // ---- now commit V to LDS (transposed), then sync ----
#pragma unroll
  for (int jj = 0; jj < 8; ++jj) {
    short8 wv;
#pragma unroll
    for (int i = 0; i < 8; ++i) wv[i] = vv[i][jj];
    *(short8*)(Vt + (size_t)(d0 + jj) * 264 + m0v) = wv;
  }
  __syncthreads();  // Vt staged before PV reads

  // PV over 3 quarters; P staged per-wave in LDS (stride 72), unnormalized
  f32x4 oacc[2][4] = {};
  unsigned short* Pw = Pb + w * (32 * 72);
  const int qlo = w >> 1;
#pragma unroll
  for (int qq = 0; qq < 3; ++qq) {
#pragma unroll
    for (int mi = 0; mi < 2; ++mi)
#pragma unroll
      for (int ni4 = 0; ni4 < 4; ++ni4)
#pragma unroll
        for (int j = 0; j < 4; ++j) {
          int r = mi * 16 + g * 4 + j;
          float val;
          if ((w & 1) == 0) {
            int u = qq * 4 + ni4;
            val = (u < 10) ? s[mi][u < 10 ? u : 0][j] : 0.0f;
          } else {
            int u = qq * 4 + ni4 - 2;
            val = (u >= 0 && u < 10) ? s[mi][(u >= 0 && u < 10) ? u : 0][j] : 0.0f;
          }
          Pw[r * 72 + ni4 * 16 + lrow] = f2bf(val);
        }
    const int qi = qlo + qq;
#pragma unroll
    for (int ks = 0; ks < 2; ++ks) {
      bf16x8 pf[2], vf[4];
#pragma unroll
      for (int mi = 0; mi < 2; ++mi)
        pf[mi] = *(const bf16x8*)&Pw[(mi * 16 + lrow) * 72 + ks * 32 + lk8];
#pragma unroll
      for (int nj = 0; nj < 4; ++nj)
        vf[nj] = *(const bf16x8*)&Vt[(nj * 16 + lrow) * 264 + qi * 64 + ks * 32 + lk8];
#pragma unroll
      for (int mi = 0; mi < 2; ++mi)
#pragma unroll
        for (int nj = 0; nj < 4; ++nj)
          oacc[mi][nj] = mfma16(pf[mi], vf[nj], oacc[mi][nj]);
    }
  }

  const int t0 = c * 128 + w * 32;
  const int n_ = nh >> 4, h_ = nh & 15;
#pragma unroll
  for (int mi = 0; mi < 2; ++mi)
#pragma unroll
    for (int nj = 0; nj < 4; ++nj)
#pragma unroll
      for (int j = 0; j < 4; ++j) {
        int t = t0 + mi * 16 + g * 4 + j;
        int dcol = nj * 16 + lrow;
        ao[((size_t)n_ * T_S + t) * D_M + h_ * 64 + dcol] =
            f2bf(oacc[mi][nj][j] * invs[mi][j]);
      }
}

extern "C" void kernel_launch(void* const* d_in, const int* in_sizes, int n_in,
                              void* d_out, int out_size, void* d_ws, size_t ws_size,
                              hipStream_t stream) {
  const float* x = (const float*)d_in[0];      // [2,4096,1024]
  const float* qkvw = (const float*)d_in[1];   // [3,1024,1024]
  const float* ow = (const float*)d_in[2];     // [1024,1024]
  const float* osc = (const float*)d_in[3];    // [1024]
  float* out = (float*)d_out;

  char* ws = (char*)d_ws;
  unsigned short* xn = (unsigned short*)(ws + 0);
  unsigned short* qkvwb = (unsigned short*)(ws + 16777216);
  unsigned short* owb = (unsigned short*)(ws + 23068672);
  unsigned short* qhb = (unsigned short*)(ws + 25165824);
  unsigned short* khb = (unsigned short*)(ws + 41943040);
  unsigned short* vhb = (unsigned short*)(ws + 58720256);
  unsigned short* aob = (unsigned short*)(ws + 75497472);
  float* cosT = (float*)(ws + 92274688);
  float* sinT = (float*)(ws + 92798976);

  // fused prologue: rmsnorm (8192) + qkvw cast (3072) + ow cast (1024) + rope table (512)
  k_prologue<<<12800, 256, 0, stream>>>(x, xn, qkvw, qkvwb, ow, owb, cosT, sinT);
  k_gemm256<0><<<dim3(24, 32), 512, 73728, stream>>>(xn, qkvwb, qhb, khb, vhb, nullptr,
                                                     nullptr, nullptr, cosT, sinT,
                                                     8192, 3072, 1024);
  k_attn<<<1024, 256, 52224, stream>>>(qhb, khb, vhb, aob);
  k_gemm256<1><<<dim3(8, 32), 512, 73728, stream>>>(aob, owb, nullptr, nullptr, nullptr,
                                                    out, x, osc, nullptr, nullptr,
                                                    8192, 1024, 1024);
}

// Round 17
// 137.933 us; speedup vs baseline: 1.0442x; 1.0040x over previous
//
#include <hip/hip_runtime.h>
#include <hip/hip_bf16.h>
#include <stdint.h>
#include <stddef.h>

#define T_S 4096
#define D_M 1024
#define NH_ 16
#define EPSF 1.1920929e-07f

typedef float f32x4 __attribute__((ext_vector_type(4)));
typedef __bf16 bf16x8 __attribute__((ext_vector_type(8)));
typedef short short8 __attribute__((ext_vector_type(8)));
typedef unsigned short ushort4v __attribute__((ext_vector_type(4)));

static __device__ __forceinline__ unsigned short f2bf(float f) {
  return __builtin_bit_cast(unsigned short, (__bf16)f);  // native RNE cvt
}

#define GLDS16(gp, lp) __builtin_amdgcn_global_load_lds( \
    (__attribute__((address_space(1))) void*)(gp),       \
    (__attribute__((address_space(3))) void*)(lp), 16, 0, 0)

static __device__ __forceinline__ f32x4 mfma16(bf16x8 a, bf16x8 b, f32x4 c) {
  return __builtin_amdgcn_mfma_f32_16x16x32_bf16(a, b, c, 0, 0, 0);
}

// ---------------- fused prologue: rmsnorm+cast | weight casts | rope table ----------------
// Block partition (cumulative, grid = 12800):
//   [0, 8192)      RMSNorm rows (8192)
//   [8192, 11264)  qkvw cast (3072 blocks x 256 thr x float4 = 786432 groups)
//   [11264, 12288) ow cast (1024 blocks = 262144 groups)
//   [12288, 12800) rope table (512 blocks = 131072 entries)
__global__ __launch_bounds__(256) void k_prologue(
    const float* __restrict__ x, unsigned short* __restrict__ xn,
    const float* __restrict__ qkvw, unsigned short* __restrict__ qkvwb,
    const float* __restrict__ ow, unsigned short* __restrict__ owb,
    float* __restrict__ cosT, float* __restrict__ sinT) {
  const int bid = blockIdx.x;
  const int tid = threadIdx.x;
  if (bid < 8192) {
    const int row = bid;
    float4 v = ((const float4*)(x + (size_t)row * D_M))[tid];
    float ss = v.x * v.x + v.y * v.y + v.z * v.z + v.w * v.w;
#pragma unroll
    for (int d = 1; d < 64; d <<= 1) ss += __shfl_xor(ss, d, 64);
    __shared__ float red[4];
    if ((tid & 63) == 0) red[tid >> 6] = ss;
    __syncthreads();
    float sc = rsqrtf((red[0] + red[1] + red[2] + red[3]) * (1.0f / D_M) + EPSF);
    ushort4v o;
    o.x = f2bf(v.x * sc); o.y = f2bf(v.y * sc);
    o.z = f2bf(v.z * sc); o.w = f2bf(v.w * sc);
    ((ushort4v*)(xn + (size_t)row * D_M))[tid] = o;
  } else if (bid < 11264) {
    int i = (bid - 8192) * 256 + tid;
    float4 v = ((const float4*)qkvw)[i];
    ushort4v o;
    o.x = f2bf(v.x); o.y = f2bf(v.y); o.z = f2bf(v.z); o.w = f2bf(v.w);
    ((ushort4v*)qkvwb)[i] = o;
  } else if (bid < 12288) {
    int i = (bid - 11264) * 256 + tid;
    float4 v = ((const float4*)ow)[i];
    ushort4v o;
    o.x = f2bf(v.x); o.y = f2bf(v.y); o.z = f2bf(v.z); o.w = f2bf(v.w);
    ((ushort4v*)owb)[i] = o;
  } else {
    int i = (bid - 12288) * 256 + tid;  // t*32 + f
    int t = i >> 5, f = i & 31;
    float fr = (f < 16) ? powf(1e-4f, (float)f * (1.0f / 15.0f)) : 0.0f;
    float th = (float)t * fr;
    cosT[i] = cosf(th);
    sinT[i] = sinf(th);
  }
}

// ---------------- bf16 GEMM, C = A @ B^T, 3-stage pipeline (R8/R13 champion) ----------------
// BM=256, BN=128, BK=32; 8 waves (4M x 2N), wave tile 64x64; 3 LDS buffers x 24KB.
// Session-closed GEMM search: schedule depth (R5-R7), occupancy coercion (R9-R10),
// wave-tile intensity (R12) all lose to this config. VGPR 56, 2 blocks/CU, vmcnt(3).
// EPI 0: fused per-head RMSNorm+RoPE scatter -> q/k/v head-major bf16 [n,h,t,d]
// EPI 1: Cf = resid + scale[col]*acc (f32)
template <int EPI>
__global__ __launch_bounds__(512) void k_gemm256(
    const unsigned short* __restrict__ A, const unsigned short* __restrict__ B,
    unsigned short* __restrict__ q_out, unsigned short* __restrict__ k_out,
    unsigned short* __restrict__ v_out, float* __restrict__ Cf,
    const float* __restrict__ resid, const float* __restrict__ scale,
    const float* __restrict__ cosT, const float* __restrict__ sinT,
    int M, int Ncols, int K) {
  extern __shared__ __align__(16) char lds[];  // 3 x (16384 A + 8192 B) = 73728 B
  const int tid = threadIdx.x;
  const int lane = tid & 63, w = tid >> 6;
  const int lrow = lane & 15, g = lane >> 4;
  const int wm = w >> 1, wn = w & 1;
  const int m0 = blockIdx.y * 256, n0 = blockIdx.x * 128;
  const int NT = K >> 5;

  const int srcgrp = (((tid & 3) ^ ((tid >> 3) & 3)) << 3);
  const size_t aoff0 = (size_t)(m0 + (tid >> 2)) * K + srcgrp;
  const size_t aoff1 = aoff0 + (size_t)128 * K;
  const size_t boff = (size_t)(n0 + (tid >> 2)) * K + srcgrp;
  const int wbase = w * 1024;

  int abyte[4], bbyte[4];
#pragma unroll
  for (int i = 0; i < 4; ++i) {
    int ar = wm * 64 + i * 16 + lrow;
    abyte[i] = ar * 64 + ((g ^ ((ar >> 1) & 3)) << 4);
    int br = wn * 64 + i * 16 + lrow;
    bbyte[i] = 16384 + br * 64 + ((g ^ ((br >> 1) & 3)) << 4);
  }

  f32x4 acc[4][4] = {};

#pragma unroll
  for (int t = 0; t < 2; ++t) {
    char* sp = lds + t * 24576;
    GLDS16(A + aoff0 + t * 32, sp + wbase);
    GLDS16(A + aoff1 + t * 32, sp + 8192 + wbase);
    GLDS16(B + boff + t * 32, sp + 16384 + wbase);
  }
  asm volatile("s_waitcnt vmcnt(3)" ::: "memory");
  __builtin_amdgcn_s_barrier();
  asm volatile("" ::: "memory");

  int cb = 0, sb = 49152;
  for (int t = 0; t < NT; ++t) {
    if (t + 2 < NT) {
      const int kt2 = (t + 2) << 5;
      char* sp = lds + sb;
      GLDS16(A + aoff0 + kt2, sp + wbase);
      GLDS16(A + aoff1 + kt2, sp + 8192 + wbase);
      GLDS16(B + boff + kt2, sp + 16384 + wbase);
    }
    const char* cp = lds + cb;
    bf16x8 aF[4], bF[4];
#pragma unroll
    for (int i = 0; i < 4; ++i) aF[i] = *(const bf16x8*)(cp + abyte[i]);
#pragma unroll
    for (int i = 0; i < 4; ++i) bF[i] = *(const bf16x8*)(cp + bbyte[i]);
    __builtin_amdgcn_s_setprio(1);
#pragma unroll
    for (int mi = 0; mi < 4; ++mi)
#pragma unroll
      for (int ni = 0; ni < 4; ++ni)
        acc[mi][ni] = mfma16(aF[mi], bF[ni], acc[mi][ni]);
    __builtin_amdgcn_s_setprio(0);
    if (t + 2 < NT)
      asm volatile("s_waitcnt vmcnt(3)" ::: "memory");
    else
      asm volatile("s_waitcnt vmcnt(0)" ::: "memory");
    __builtin_amdgcn_s_barrier();
    asm volatile("" ::: "memory");
    cb += 24576; if (cb == 73728) cb = 0;
    sb += 24576; if (sb == 73728) sb = 0;
  }

  const int rbase = m0 + wm * 64 + g * 4;  // + mi*16 + j
  const int colbase = n0 + wn * 64;        // wave covers exactly one head

  if (EPI == 1) {
#pragma unroll
    for (int mi = 0; mi < 4; ++mi)
#pragma unroll
      for (int nf = 0; nf < 4; ++nf) {
        int col = colbase + nf * 16 + lrow;
        float sc = scale[col];
#pragma unroll
        for (int j = 0; j < 4; ++j) {
          int row = rbase + mi * 16 + j;
          size_t idx = (size_t)row * Ncols + col;
          Cf[idx] = resid[idx] + sc * acc[mi][nf][j];
        }
      }
  } else {
    const int which = colbase >> 10;
    const int hh = (colbase >> 6) & 15;
    if (which == 2) {
#pragma unroll
      for (int mi = 0; mi < 4; ++mi)
#pragma unroll
        for (int j = 0; j < 4; ++j) {
          int row = rbase + mi * 16 + j;
          int t = row & (T_S - 1), nn = row >> 12;
          size_t ob = ((size_t)(nn * NH_ + hh) * T_S + t) * 64;
#pragma unroll
          for (int nf = 0; nf < 4; ++nf)
            v_out[ob + nf * 16 + lrow] = f2bf(acc[mi][nf][j]);
        }
    } else {
      unsigned short* dst = which ? k_out : q_out;
#pragma unroll
      for (int mi = 0; mi < 4; ++mi)
#pragma unroll
        for (int j = 0; j < 4; ++j) {
          int row = rbase + mi * 16 + j;
          int t = row & (T_S - 1), nn = row >> 12;
          float ss = 0.0f;
#pragma unroll
          for (int nf = 0; nf < 4; ++nf) ss += acc[mi][nf][j] * acc[mi][nf][j];
          ss += __shfl_xor(ss, 1, 64);
          ss += __shfl_xor(ss, 2, 64);
          ss += __shfl_xor(ss, 4, 64);
          ss += __shfl_xor(ss, 8, 64);
          float sc = rsqrtf(ss * (1.0f / 64.0f) + EPSF);
          size_t ob = ((size_t)(nn * NH_ + hh) * T_S + t) * 64;
#pragma unroll
          for (int nf = 0; nf < 2; ++nf) {
            int dd = nf * 16 + lrow;
            float cs = cosT[t * 32 + dd], sn = sinT[t * 32 + dd];
            float z1 = acc[mi][nf][j] * sc, z2 = acc[mi][nf + 2][j] * sc;
            dst[ob + dd] = f2bf(z1 * cs + z2 * sn);
            dst[ob + dd + 32] = f2bf(z2 * cs - z1 * sn);
          }
        }
    }
  }
}

// ---------------- chunked sliding-window attention: 2 chunks/block, cross-chunk V prefetch ----
// block = (n,h,cpair): chunks c0=2*cpair, c1=c0+1. Chunk c1's V global loads issue
// right after chunk c0's V->LDS commit (vv registers freed), hiding their HBM
// latency under c0's PV + O-write + c1's QK/softmax. VGPR unchanged (vv reused).
__global__ __launch_bounds__(256, 2) void k_attn(const unsigned short* __restrict__ qh,
                                                 const unsigned short* __restrict__ kh,
                                                 const unsigned short* __restrict__ vh,
                                                 unsigned short* __restrict__ ao) {
  extern __shared__ __align__(16) char lds[];
  unsigned short* Vt = (unsigned short*)lds;                    // [64][264]
  unsigned short* Pb = (unsigned short*)(lds + 64 * 264 * 2);   // 4 x [32][72]
  const int b = blockIdx.x;  // 512 blocks
  const int cpair = b & 15, nh = b >> 4;
  const int tid = threadIdx.x, lane = tid & 63, w = tid >> 6;
  const int lrow = lane & 15, g = lane >> 4, lk8 = g * 8;
  const size_t hb = (size_t)nh * T_S * 64;

  const int m_idx = (tid & 7) | ((tid >> 6) << 3);
  const int m0v = m_idx * 8;
  const int d0 = ((tid >> 3) & 7) * 8;
  const int n_ = nh >> 4, h_ = nh & 15;

  short8 vv[8];
  // prefetch V for first chunk
  {
    const int c = 2 * cpair;
    const unsigned short* vg = vh + hb + ((ptrdiff_t)c * 128 - 128) * 64;
#pragma unroll
    for (int i = 0; i < 8; ++i) {
      short8 z = {0, 0, 0, 0, 0, 0, 0, 0};
      if (!(c == 0 && m0v < 128)) z = *(const short8*)(vg + (size_t)(m0v + i) * 64 + d0);
      vv[i] = z;
    }
  }

#pragma unroll
  for (int ci = 0; ci < 2; ++ci) {
    const int c = 2 * cpair + ci;
    const unsigned short* qg = qh + hb + (size_t)c * 128 * 64;
    const unsigned short* kg = kh + hb + ((ptrdiff_t)c * 128 - 128) * 64;

    // Q fragments
    bf16x8 qf[2][2];
#pragma unroll
    for (int mi = 0; mi < 2; ++mi)
#pragma unroll
      for (int ks = 0; ks < 2; ++ks)
        qf[mi][ks] =
            *(const bf16x8*)(qg + (size_t)(w * 32 + mi * 16 + lrow) * 64 + ks * 32 + lk8);

    // S = Q K^T over the wave's 10-tile window
    const int nlo = 2 * w;
    f32x4 s[2][10] = {};
#pragma unroll
    for (int u = 0; u < 10; ++u) {
      const int ni = nlo + u;
      if (c == 0 && ni < 8) continue;
      bf16x8 kf0 = *(const bf16x8*)(kg + (size_t)(ni * 16 + lrow) * 64 + lk8);
      bf16x8 kf1 = *(const bf16x8*)(kg + (size_t)(ni * 16 + lrow) * 64 + 32 + lk8);
#pragma unroll
      for (int mi = 0; mi < 2; ++mi) {
        s[mi][u] = mfma16(qf[mi][0], kf0, s[mi][u]);
        s[mi][u] = mfma16(qf[mi][1], kf1, s[mi][u]);
      }
    }

    // mask + scale + row softmax (deferred normalization)
    float invs[2][4];
#pragma unroll
    for (int mi = 0; mi < 2; ++mi) {
#pragma unroll
      for (int j = 0; j < 4; ++j) {
        int jq = w * 32 + mi * 16 + g * 4 + j;
        float mx = -1e30f;
#pragma unroll
        for (int u = 0; u < 10; ++u) {
          int m = (nlo + u) * 16 + lrow;
          bool ok = (m > jq) && (m <= 128 + jq) && (c > 0 || m >= 128);
          float val = ok ? s[mi][u][j] * 0.125f : -1e30f;
          s[mi][u][j] = val;
          mx = fmaxf(mx, val);
        }
#pragma unroll
        for (int d2 = 1; d2 < 16; d2 <<= 1) mx = fmaxf(mx, __shfl_xor(mx, d2, 64));
        float sum = 0.0f;
#pragma unroll
        for (int u = 0; u < 10; ++u) {
          float p = __expf(s[mi][u][j] - mx);
          s[mi][u][j] = p;
          sum += p;
        }
#pragma unroll
        for (int d2 = 1; d2 < 16; d2 <<= 1) sum += __shfl_xor(sum, d2, 64);
        invs[mi][j] = 1.0f / sum;
      }
    }

    // commit V (current chunk) to LDS transposed, then sync
#pragma unroll
    for (int jj = 0; jj < 8; ++jj) {
      short8 wv;
#pragma unroll
      for (int i = 0; i < 8; ++i) wv[i] = vv[i][jj];
      *(short8*)(Vt + (size_t)(d0 + jj) * 264 + m0v) = wv;
    }
    __syncthreads();  // Vt staged before PV reads

    // vv registers free: prefetch next chunk's V (latency hides under PV + next QK)
    if (ci == 0) {
      const unsigned short* vg1 = vh + hb + ((ptrdiff_t)(c + 1) * 128 - 128) * 64;
#pragma unroll
      for (int i = 0; i < 8; ++i)
        vv[i] = *(const short8*)(vg1 + (size_t)(m0v + i) * 64 + d0);
    }

    // PV over 3 quarters; P staged per-wave in LDS (stride 72), unnormalized
    f32x4 oacc[2][4] = {};
    unsigned short* Pw = Pb + w * (32 * 72);
    const int qlo = w >> 1;
#pragma unroll
    for (int qq = 0; qq < 3; ++qq) {
#pragma unroll
      for (int mi = 0; mi < 2; ++mi)
#pragma unroll
        for (int ni4 = 0; ni4 < 4; ++ni4)
#pragma unroll
          for (int j = 0; j < 4; ++j) {
            int r = mi * 16 + g * 4 + j;
            float val;
            if ((w & 1) == 0) {
              int u = qq * 4 + ni4;
              val = (u < 10) ? s[mi][u < 10 ? u : 0][j] : 0.0f;
            } else {
              int u = qq * 4 + ni4 - 2;
              val = (u >= 0 && u < 10) ? s[mi][(u >= 0 && u < 10) ? u : 0][j] : 0.0f;
            }
            Pw[r * 72 + ni4 * 16 + lrow] = f2bf(val);
          }
      const int qi = qlo + qq;
#pragma unroll
      for (int ks = 0; ks < 2; ++ks) {
        bf16x8 pf[2], vf[4];
#pragma unroll
        for (int mi = 0; mi < 2; ++mi)
          pf[mi] = *(const bf16x8*)&Pw[(mi * 16 + lrow) * 72 + ks * 32 + lk8];
#pragma unroll
        for (int nj = 0; nj < 4; ++nj)
          vf[nj] = *(const bf16x8*)&Vt[(nj * 16 + lrow) * 264 + qi * 64 + ks * 32 + lk8];
#pragma unroll
        for (int mi = 0; mi < 2; ++mi)
#pragma unroll
          for (int nj = 0; nj < 4; ++nj)
            oacc[mi][nj] = mfma16(pf[mi], vf[nj], oacc[mi][nj]);
      }
    }

    // write attention out, token-major [n*T+t][h*64+d] bf16
    const int t0 = c * 128 + w * 32;
#pragma unroll
    for (int mi = 0; mi < 2; ++mi)
#pragma unroll
      for (int nj = 0; nj < 4; ++nj)
#pragma unroll
        for (int j = 0; j < 4; ++j) {
          int t = t0 + mi * 16 + g * 4 + j;
          int dcol = nj * 16 + lrow;
          ao[((size_t)n_ * T_S + t) * D_M + h_ * 64 + dcol] =
              f2bf(oacc[mi][nj][j] * invs[mi][j]);
        }

    if (ci == 0) __syncthreads();  // all PV reads of Vt done before next commit
  }
}

extern "C" void kernel_launch(void* const* d_in, const int* in_sizes, int n_in,
                              void* d_out, int out_size, void* d_ws, size_t ws_size,
                              hipStream_t stream) {
  const float* x = (const float*)d_in[0];      // [2,4096,1024]
  const float* qkvw = (const float*)d_in[1];   // [3,1024,1024]
  const float* ow = (const float*)d_in[2];     // [1024,1024]
  const float* osc = (const float*)d_in[3];    // [1024]
  float* out = (float*)d_out;

  char* ws = (char*)d_ws;
  unsigned short* xn = (unsigned short*)(ws + 0);
  unsigned short* qkvwb = (unsigned short*)(ws + 16777216);
  unsigned short* owb = (unsigned short*)(ws + 23068672);
  unsigned short* qhb = (unsigned short*)(ws + 25165824);
  unsigned short* khb = (unsigned short*)(ws + 41943040);
  unsigned short* vhb = (unsigned short*)(ws + 58720256);
  unsigned short* aob = (unsigned short*)(ws + 75497472);
  float* cosT = (float*)(ws + 92274688);
  float* sinT = (float*)(ws + 92798976);

  k_prologue<<<12800, 256, 0, stream>>>(x, xn, qkvw, qkvwb, ow, owb, cosT, sinT);
  k_gemm256<0><<<dim3(24, 32), 512, 73728, stream>>>(xn, qkvwb, qhb, khb, vhb, nullptr,
                                                     nullptr, nullptr, cosT, sinT,
                                                     8192, 3072, 1024);
  k_attn<<<512, 256, 52224, stream>>>(qhb, khb, vhb, aob);
  k_gemm256<1><<<dim3(8, 32), 512, 73728, stream>>>(aob, owb, nullptr, nullptr, nullptr,
                                                    out, x, osc, nullptr, nullptr,
                                                    8192, 1024, 1024);
}